// Round 8
// baseline (288.822 us; speedup 1.0000x reference)
//
#include <hip/hip_runtime.h>

#define NCLS 13
#define DIM  256
#define INV_T (1.0f/0.07f)

typedef short bf16x8 __attribute__((ext_vector_type(8)));
typedef float f32x4  __attribute__((ext_vector_type(4)));

__device__ __forceinline__ float bf2f(unsigned short u){
  union { unsigned u; float f; } v; v.u = ((unsigned)u) << 16; return v.f;
}
__device__ __forceinline__ unsigned short f2bf(float f){
  union { float f; unsigned u; } v; v.f = f;
  unsigned r = v.u + 0x7fffu + ((v.u >> 16) & 1u);
  return (unsigned short)(r >> 16);
}

__device__ __forceinline__ void gload_lds16(const void* g, void* l){
  __builtin_amdgcn_global_load_lds((const __attribute__((address_space(1))) unsigned*)g,
                                   (__attribute__((address_space(3))) unsigned*)l, 16, 0, 0);
}

// ---------------- prep kernels ----------------

__global__ void k_zero(int* counts, unsigned* packLab, double* accum, int n, int np){
  int i = blockIdx.x*blockDim.x + threadIdx.x;
  if (i < n)  counts[i] = 0;
  if (i < np) packLab[i] = 0u;
  if (i == 0) *accum = 0.0;
}

__global__ void k_hist(const int* __restrict__ idx, const int* __restrict__ lab,
                       int* __restrict__ counts, int n){
  int i = blockIdx.x*blockDim.x + threadIdx.x;
  if (i < n) atomicAdd(&counts[idx[i]*NCLS + lab[i]], 1);
}

// one block, M threads (M=1024). argmax labels + label-sorted permutation +
// nibble-packed column labels: packLab[chunk*16 + (pos&15)] nibble ((pos>>4)&7).
__global__ void k_label_perm(const int* __restrict__ counts, int* __restrict__ spLabel,
                             int* __restrict__ newpos, unsigned* __restrict__ packLab){
  int m = threadIdx.x;
  int best = 0; int bc = counts[m*NCLS];
  #pragma unroll
  for (int c = 1; c < NCLS; ++c){ int v = counts[m*NCLS+c]; if (v > bc){ bc = v; best = c; } }
  spLabel[m] = best;

  __shared__ int waveCnt[16][NCLS];
  __shared__ int waveOff[16][NCLS];
  __shared__ int classTot[NCLS];
  __shared__ int classBase[NCLS];
  int lane = m & 63, wid = m >> 6;
  int nw = blockDim.x >> 6;
  int rankInWave = 0;
  unsigned long long below = (1ull << lane) - 1ull;
  for (int c = 0; c < NCLS; ++c){
    unsigned long long bal = __ballot(best == c);
    if (best == c) rankInWave = __popcll(bal & below);
    if (lane == 0) waveCnt[wid][c] = __popcll(bal);
  }
  __syncthreads();
  if (m < NCLS){
    int c = m, s = 0;
    for (int w = 0; w < nw; ++w){ waveOff[w][c] = s; s += waveCnt[w][c]; }
    classTot[c] = s;
  }
  __syncthreads();
  if (m == 0){ int s = 0; for (int c = 0; c < NCLS; ++c){ classBase[c] = s; s += classTot[c]; } }
  __syncthreads();
  int pos = classBase[best] + waveOff[wid][best] + rankInWave;
  newpos[m] = pos;
  atomicOr(&packLab[(pos >> 7)*16 + (pos & 15)], (unsigned)best << (((pos >> 4) & 7)*4));
}

// one wave per superpoint row: normalize, write bf16 in original and permuted order
__global__ void k_norm_sp(const float* __restrict__ sp, const int* __restrict__ newpos,
                          unsigned short* __restrict__ spnO, unsigned short* __restrict__ spnP){
  int m = blockIdx.x, lane = threadIdx.x;
  const float4 v = *(const float4*)(sp + (size_t)m*DIM + lane*4);
  float ss = v.x*v.x + v.y*v.y + v.z*v.z + v.w*v.w;
  #pragma unroll
  for (int o = 1; o < 64; o <<= 1) ss += __shfl_xor(ss, o);
  float rn = 1.0f / sqrtf(ss + 1e-12f);
  uint2 w;
  w.x = (unsigned)f2bf(v.x*rn) | ((unsigned)f2bf(v.y*rn) << 16);
  w.y = (unsigned)f2bf(v.z*rn) | ((unsigned)f2bf(v.w*rn) << 16);
  *(uint2*)(spnO + (size_t)m*DIM + lane*4) = w;
  int p = newpos[m];
  *(uint2*)(spnP + (size_t)p*DIM + lane*4) = w;
}

// ---------------- main fused GEMM ----------------
// 512 threads = 8 waves; wave owns 64 rows x ALL 1024 cols; BM = 512, grid 256
// (1 block/CU). A: registers a[4][8] (128 VGPR), scaled by INV_T, staged via
// Bsh[1] in 4 same-wave passes of 16 rows. B: LDS double-buffered 64 KB chunks,
// counted vmcnt + raw s_barrier (R7-verified). No global loads inside the loop.
// LDS-read/CU = 8 waves x 512 KB = 4 MB (half of R7's per-CU traffic).

#define SBAR()   __builtin_amdgcn_s_barrier()
#define SFENCE() __builtin_amdgcn_sched_barrier(0)

__device__ __forceinline__ void stageB(const unsigned short* __restrict__ spnP,
                                       void* buf, int c, int tid){
  const int wid = tid >> 6;
  #pragma unroll
  for (int i = 0; i < 8; ++i){
    const int d    = i*8192 + tid*16;      // linear dst byte in 64 KB chunk
    const int colp = d >> 9;               // 512 B per column (256 k * 2B)
    const int x    = d & 511;
    const char* src = (const char*)spnP + (size_t)(c*128 + colp)*512 + (x ^ ((colp & 7) << 4));
    char* dst = (char*)buf + i*8192 + wid*1024;   // wave-uniform; HW adds lane*16
    gload_lds16(src, dst);
  }
}

__attribute__((amdgpu_waves_per_eu(1, 2)))
__launch_bounds__(512)
__global__ void k_main(const float* __restrict__ rp, const int* __restrict__ rawIdx,
                       const unsigned short* __restrict__ spnO, const unsigned short* __restrict__ spnP,
                       const unsigned* __restrict__ packLab, const int* __restrict__ spLabel,
                       double* __restrict__ accum, int M){
  __shared__ __align__(16) unsigned short Bsh[2][128*256];  // 128 KB; Bsh[1] doubles as A staging
  __shared__ unsigned cpLds[128];

  const int tid  = threadIdx.x;
  const int lane = tid & 63, wid = tid >> 6;
  const int l15  = lane & 15, l4 = lane >> 4;
  const int rowBlock = blockIdx.x * 512;

  stageB(spnP, &Bsh[0][0], 0, tid);            // chunk 0 in flight under prologue
  if (tid < 128) cpLds[tid] = packLab[tid];    // all column labels -> LDS

  // per-lane row metadata: lane l holds row (wid*64+l)
  const int sidxv = rawIdx[rowBlock + wid*64 + lane];
  const int slabv = spLabel[sidxv];

  char* Ast = (char*)&Bsh[1][0];               // 128 slots x 512 B
  bf16x8 a[4][8];
  float dlv = 0.f;                             // lane l accumulates row-l's pos logit

  #pragma unroll
  for (int p = 0; p < 4; ++p){
    #pragma unroll 2
    for (int rr = 0; rr < 16; ++rr){
      const int rl  = p*16 + rr;               // wave-local row
      const float4 v = *(const float4*)(rp + (size_t)(rowBlock + wid*64 + rl)*DIM + lane*4);
      float ss = v.x*v.x + v.y*v.y + v.z*v.z + v.w*v.w;
      #pragma unroll
      for (int o = 1; o < 64; o <<= 1) ss += __shfl_xor(ss, o);
      const float rn = INV_T / sqrtf(ss + 1e-12f);   // fold 1/T into A
      uint2 w;
      w.x = (unsigned)f2bf(v.x*rn) | ((unsigned)f2bf(v.y*rn) << 16);
      w.y = (unsigned)f2bf(v.z*rn) | ((unsigned)f2bf(v.w*rn) << 16);
      const int slot = wid*16 + rr;
      *(uint2*)(Ast + slot*512 + ((lane*8) ^ ((slot & 7) << 4))) = w;
      const int sidx = __shfl(sidxv, rl);
      const uint2 sv = *(const uint2*)(spnO + (size_t)sidx*DIM + lane*4);
      float dd = bf2f(w.x & 0xffff)*bf2f(sv.x & 0xffff)
               + bf2f(w.x >> 16)  *bf2f(sv.x >> 16)
               + bf2f(w.y & 0xffff)*bf2f(sv.y & 0xffff)
               + bf2f(w.y >> 16)  *bf2f(sv.y >> 16);
      #pragma unroll
      for (int o = 1; o < 64; o <<= 1) dd += __shfl_xor(dd, o);
      dlv = (lane == rl) ? dd : dlv;
    }
    // frag reads: rows p*16+l15 staged by THIS wave (same-wave LDS ordering)
    #pragma unroll
    for (int kf = 0; kf < 8; ++kf){
      const int slot = wid*16 + l15;
      a[p][kf] = *(const bf16x8*)(Ast + slot*512 + ((kf*64 + l4*16) ^ ((l15 & 7) << 4)));
    }
  }

  // row labels nibble-packed: ri = rf*4+e -> wave-local row rf*16 + l4*4 + e
  unsigned Lp0 = 0, Lp1 = 0;
  #pragma unroll
  for (int rf = 0; rf < 4; ++rf)
    #pragma unroll
    for (int e = 0; e < 4; ++e){
      unsigned lb = (unsigned)__shfl(slabv, rf*16 + l4*4 + e);
      int ri = rf*4 + e;
      if (rf < 2) Lp0 |= lb << (ri*4);
      else        Lp1 |= lb << ((ri - 8)*4);
    }

  float sumT[16], sumO[16];
  #pragma unroll
  for (int i = 0; i < 16; ++i){ sumT[i] = 0.f; sumO[i] = 0.f; }

  __syncthreads();   // A frags read everywhere; Bsh[1] free; chunk0 drained

  for (int c = 0; c < 8; ++c){
    if (c + 1 < 8) stageB(spnP, &Bsh[(c+1)&1][0], c+1, tid);
    const unsigned cpack = cpLds[c*16 + l15];   // LDS, no vmcnt interaction
    if (c + 1 < 8) asm volatile("s_waitcnt vmcnt(8)" ::: "memory");
    else           asm volatile("s_waitcnt vmcnt(0)" ::: "memory");
    SFENCE(); SBAR(); SFENCE();

    const char* Bp = (const char*)&Bsh[c&1][0];
    #pragma unroll
    for (int cf = 0; cf < 8; ++cf){
      const int colp = cf*16 + l15;
      const int swz  = (colp & 7) << 4;
      f32x4 acc[4];
      #pragma unroll
      for (int rf = 0; rf < 4; ++rf) acc[rf] = (f32x4){0.f,0.f,0.f,0.f};
      #pragma unroll
      for (int kh = 0; kh < 2; ++kh){
        bf16x8 b[4];
        #pragma unroll
        for (int kq = 0; kq < 4; ++kq)
          b[kq] = *(const bf16x8*)(Bp + colp*512 + (((kh*4+kq)*64 + l4*16) ^ swz));
        #pragma unroll
        for (int kq = 0; kq < 4; ++kq)
          #pragma unroll
          for (int rf = 0; rf < 4; ++rf)
            acc[rf] = __builtin_amdgcn_mfma_f32_16x16x32_bf16(a[rf][kh*4+kq], b[kq], acc[rf], 0, 0, 0);
      }
      const unsigned colLab = (cpack >> (cf*4)) & 15u;
      #pragma unroll
      for (int rf = 0; rf < 4; ++rf)
        #pragma unroll
        for (int e = 0; e < 4; ++e){
          const float ev = __expf(acc[rf][e]);   // INV_T already folded into A
          const int ri = rf*4 + e;
          const unsigned lr = ((rf < 2 ? Lp0 : Lp1) >> ((ri & 7)*4)) & 15u;
          sumT[ri] += ev;
          sumO[ri] += (lr == colLab) ? ev : 0.f;
        }
    }
    SFENCE(); SBAR(); SFENCE();
  }

  // reduce over the 16 l15-lanes sharing each row
  #pragma unroll
  for (int i = 0; i < 16; ++i){
    #pragma unroll
    for (int o = 1; o < 16; o <<= 1){
      sumT[i] += __shfl_xor(sumT[i], o);
      sumO[i] += __shfl_xor(sumO[i], o);
    }
  }

  // all lanes compute (shfls need full wave); mask to l15==0, reduce, 1 atomic/wave
  float part = 0.f;
  #pragma unroll
  for (int rf = 0; rf < 4; ++rf)
    #pragma unroll
    for (int e = 0; e < 4; ++e){
      const int rl = rf*16 + l4*4 + e;
      const float d  = __shfl(dlv, rl);          // scaled pos logit
      const float ep = __expf(d);
      const float den = ep + (sumT[rf*4+e] - sumO[rf*4+e]) + 1e-8f;
      part += __logf(den) - d;
    }
  part = (l15 == 0) ? part : 0.f;
  #pragma unroll
  for (int o = 1; o < 64; o <<= 1) part += __shfl_xor(part, o);
  if (lane == 0) atomicAdd(accum, (double)part);
}

__global__ void k_final(const double* __restrict__ accum, float* __restrict__ out, int N){
  out[0] = (float)((*accum / (double)N) * 0.07);
}

// ---------------- launch ----------------

extern "C" void kernel_launch(void* const* d_in, const int* in_sizes, int n_in,
                              void* d_out, int out_size, void* d_ws, size_t ws_size,
                              hipStream_t stream){
  const float* sp  = (const float*)d_in[0];
  const float* rp  = (const float*)d_in[1];
  const int*   idx = (const int*)d_in[2];
  const int*   lab = (const int*)d_in[3];
  const int M = in_sizes[0] / DIM;     // 1024
  const int N = in_sizes[2];           // 131072

  char* ws = (char*)d_ws;
  size_t off = 0;
  auto alloc = [&](size_t bytes){ void* p = ws + off; off = (off + bytes + 255) & ~(size_t)255; return p; };
  int*      counts  = (int*)     alloc((size_t)M * NCLS * 4);
  int*      spLabel = (int*)     alloc((size_t)M * 4);
  int*      newpos  = (int*)     alloc((size_t)M * 4);
  unsigned* packLab = (unsigned*)alloc((size_t)(M/128) * 16 * 4);
  double*   accum   = (double*)  alloc(16);
  unsigned short* spnO = (unsigned short*)alloc((size_t)M * DIM * 2);
  unsigned short* spnP = (unsigned short*)alloc((size_t)M * DIM * 2);

  k_zero<<<(M*NCLS + 255)/256, 256, 0, stream>>>(counts, packLab, accum, M*NCLS, (M/128)*16);
  k_hist<<<(N + 255)/256, 256, 0, stream>>>(idx, lab, counts, N);
  k_label_perm<<<1, M, 0, stream>>>(counts, spLabel, newpos, packLab);
  k_norm_sp<<<M, 64, 0, stream>>>(sp, newpos, spnO, spnP);
  k_main<<<N/512, 512, 0, stream>>>(rp, idx, spnO, spnP, packLab, spLabel, accum, M);
  k_final<<<1, 1, 0, stream>>>(accum, (float*)d_out, N);
}

// Round 9
// 153.034 us; speedup vs baseline: 1.8873x; 1.8873x over previous
//
#include <hip/hip_runtime.h>

#define NCLS 13
#define DIM  256
// (1/0.07) * log2(e): folds temperature AND exp2-domain conversion into A's scale
#define SCL  20.609929155f

typedef short bf16x8 __attribute__((ext_vector_type(8)));
typedef float f32x4  __attribute__((ext_vector_type(4)));

__device__ __forceinline__ float bf2f(unsigned u16){
  union { unsigned u; float f; } v; v.u = u16 << 16; return v.f;
}
__device__ __forceinline__ unsigned f2bf(float f){
  union { float f; unsigned u; } v; v.f = f;
  unsigned r = v.u + 0x7fffu + ((v.u >> 16) & 1u);
  return r >> 16;
}

__device__ __forceinline__ void gload_lds16(const void* g, void* l){
  __builtin_amdgcn_global_load_lds((const __attribute__((address_space(1))) unsigned*)g,
                                   (__attribute__((address_space(3))) unsigned*)l, 16, 0, 0);
}

// ---------------- prep kernels ----------------

__global__ void k_zero(int* counts, unsigned* packLab, double* accum, int n, int np){
  int i = blockIdx.x*blockDim.x + threadIdx.x;
  if (i < n)  counts[i] = 0;
  if (i < np) packLab[i] = 0u;
  if (i == 0) *accum = 0.0;
}

__global__ void k_hist(const int* __restrict__ idx, const int* __restrict__ lab,
                       int* __restrict__ counts, int n){
  int i = blockIdx.x*blockDim.x + threadIdx.x;
  if (i < n) atomicAdd(&counts[idx[i]*NCLS + lab[i]], 1);
}

// one block, M threads. argmax labels + label-sorted permutation + nibble-packed
// column labels for 64-col chunks: packLab[(pos>>6)*16 + (pos&15)], nibble (pos>>4)&3.
__global__ void k_label_perm(const int* __restrict__ counts, int* __restrict__ spLabel,
                             int* __restrict__ newpos, unsigned* __restrict__ packLab){
  int m = threadIdx.x;
  int best = 0; int bc = counts[m*NCLS];
  #pragma unroll
  for (int c = 1; c < NCLS; ++c){ int v = counts[m*NCLS+c]; if (v > bc){ bc = v; best = c; } }
  spLabel[m] = best;

  __shared__ int waveCnt[16][NCLS];
  __shared__ int waveOff[16][NCLS];
  __shared__ int classTot[NCLS];
  __shared__ int classBase[NCLS];
  int lane = m & 63, wid = m >> 6;
  int nw = blockDim.x >> 6;
  int rankInWave = 0;
  unsigned long long below = (1ull << lane) - 1ull;
  for (int c = 0; c < NCLS; ++c){
    unsigned long long bal = __ballot(best == c);
    if (best == c) rankInWave = __popcll(bal & below);
    if (lane == 0) waveCnt[wid][c] = __popcll(bal);
  }
  __syncthreads();
  if (m < NCLS){
    int c = m, s = 0;
    for (int w = 0; w < nw; ++w){ waveOff[w][c] = s; s += waveCnt[w][c]; }
    classTot[c] = s;
  }
  __syncthreads();
  if (m == 0){ int s = 0; for (int c = 0; c < NCLS; ++c){ classBase[c] = s; s += classTot[c]; } }
  __syncthreads();
  int pos = classBase[best] + waveOff[wid][best] + rankInWave;
  newpos[m] = pos;
  atomicOr(&packLab[(pos >> 6)*16 + (pos & 15)], (unsigned)best << (((pos >> 4) & 3)*4));
}

// one wave per superpoint row: normalize, write bf16 in original and permuted order
__global__ void k_norm_sp(const float* __restrict__ sp, const int* __restrict__ newpos,
                          unsigned short* __restrict__ spnO, unsigned short* __restrict__ spnP){
  int m = blockIdx.x, lane = threadIdx.x;
  const float4 v = *(const float4*)(sp + (size_t)m*DIM + lane*4);
  float ss = v.x*v.x + v.y*v.y + v.z*v.z + v.w*v.w;
  #pragma unroll
  for (int o = 1; o < 64; o <<= 1) ss += __shfl_xor(ss, o);
  float rn = 1.0f / sqrtf(ss + 1e-12f);
  uint2 w;
  w.x = f2bf(v.x*rn) | (f2bf(v.y*rn) << 16);
  w.y = f2bf(v.z*rn) | (f2bf(v.w*rn) << 16);
  *(uint2*)(spnO + (size_t)m*DIM + lane*4) = w;
  int p = newpos[m];
  *(uint2*)(spnP + (size_t)p*DIM + lane*4) = w;
}

// ---------------- main fused GEMM ----------------
// 512 threads = 8 waves; wave owns 32 rows (A in regs, a[2][8] = 64 VGPR) x all
// 1024 cols. BM=256. B: 16 chunks of 64 cols x K=256 (32 KB), double-buffered,
// depth-2 prefetch, uniform vmcnt(4) + raw s_barrier (R7-verified skeleton).
// LDS 67 KB -> 2 blocks/CU = 4 waves/SIMD (2x R7's occupancy).

#define SBAR()   __builtin_amdgcn_s_barrier()
#define SFENCE() __builtin_amdgcn_sched_barrier(0)

__device__ __forceinline__ void stageB(const unsigned short* __restrict__ spnP,
                                       void* buf, int c, int tid){
  const int wid = tid >> 6;
  #pragma unroll
  for (int i = 0; i < 4; ++i){
    const int d    = i*8192 + tid*16;      // linear dst byte in 32 KB chunk
    const int colp = d >> 9;               // 512 B per column (256 k * 2B)
    const int x    = d & 511;
    const char* src = (const char*)spnP + (size_t)(c*64 + colp)*512 + (x ^ ((colp & 7) << 4));
    char* dst = (char*)buf + i*8192 + wid*1024;   // wave-uniform; HW adds lane*16
    gload_lds16(src, dst);
  }
}

__attribute__((amdgpu_waves_per_eu(1, 2)))
__launch_bounds__(512)
__global__ void k_main(const float* __restrict__ rp, const int* __restrict__ rawIdx,
                       const unsigned short* __restrict__ spnO, const unsigned short* __restrict__ spnP,
                       const unsigned* __restrict__ packLab, const int* __restrict__ spLabel,
                       double* __restrict__ accum, int M){
  __shared__ __align__(16) unsigned short Bsh[2][64*256];  // 64 KB; doubles as A staging
  __shared__ float    posLt[256];
  __shared__ int      posLb[256];
  __shared__ unsigned cpLds[256];

  const int tid  = threadIdx.x;
  const int lane = tid & 63, wid = tid >> 6;
  const int l15  = lane & 15, l4 = lane >> 4;
  const int rowBlock = blockIdx.x * 256;
  char* Ast = (char*)&Bsh[0][0];           // 128 slots x 512 B during prologue

  if (tid < 256) cpLds[tid] = packLab[tid];
  if (lane < 32){
    int r = wid*32 + lane;
    posLb[r] = spLabel[rawIdx[rowBlock + r]];
  }

  // ---- prologue: 16-lane-split loader; 4 rows per iteration ----
  // lane(l4,l15): row it*4+l4, elems l15*16..+15. Reduce = 4-stage shuffle.
  bf16x8 a[2][8];
  #pragma unroll
  for (int p = 0; p < 2; ++p){
    for (int it = 0; it < 4; ++it){
      const int rl = p*16 + it*4 + l4;                 // wave-local row
      const float* rpp = rp + (size_t)(rowBlock + wid*32 + rl)*DIM + l15*16;
      const float4 v0 = *(const float4*)(rpp);
      const float4 v1 = *(const float4*)(rpp + 4);
      const float4 v2 = *(const float4*)(rpp + 8);
      const float4 v3 = *(const float4*)(rpp + 12);
      float ss = v0.x*v0.x + v0.y*v0.y + v0.z*v0.z + v0.w*v0.w
               + v1.x*v1.x + v1.y*v1.y + v1.z*v1.z + v1.w*v1.w
               + v2.x*v2.x + v2.y*v2.y + v2.z*v2.z + v2.w*v2.w
               + v3.x*v3.x + v3.y*v3.y + v3.z*v3.z + v3.w*v3.w;
      ss += __shfl_xor(ss, 1); ss += __shfl_xor(ss, 2);
      ss += __shfl_xor(ss, 4); ss += __shfl_xor(ss, 8);
      const float rn = SCL / sqrtf(ss + 1e-12f);
      uint4 w0, w1;
      w0.x = f2bf(v0.x*rn) | (f2bf(v0.y*rn) << 16);
      w0.y = f2bf(v0.z*rn) | (f2bf(v0.w*rn) << 16);
      w0.z = f2bf(v1.x*rn) | (f2bf(v1.y*rn) << 16);
      w0.w = f2bf(v1.z*rn) | (f2bf(v1.w*rn) << 16);
      w1.x = f2bf(v2.x*rn) | (f2bf(v2.y*rn) << 16);
      w1.y = f2bf(v2.z*rn) | (f2bf(v2.w*rn) << 16);
      w1.z = f2bf(v3.x*rn) | (f2bf(v3.y*rn) << 16);
      w1.w = f2bf(v3.z*rn) | (f2bf(v3.w*rn) << 16);
      const int slot = wid*16 + it*4 + l4;
      const int swz  = (slot & 7) << 4;
      char* dstb = Ast + slot*512;
      *(uint4*)(dstb + ((l15*32)      ^ swz)) = w0;
      *(uint4*)(dstb + ((l15*32 + 16) ^ swz)) = w1;
      // positive logit (dot of SCL-scaled bf16 A row with spnO row)
      const int sidx = rawIdx[rowBlock + wid*32 + rl];
      const uint4 s0 = *(const uint4*)(spnO + (size_t)sidx*DIM + l15*16);
      const uint4 s1 = *(const uint4*)(spnO + (size_t)sidx*DIM + l15*16 + 8);
      float d =
        bf2f(w0.x & 0xffff)*bf2f(s0.x & 0xffff) + bf2f(w0.x >> 16)*bf2f(s0.x >> 16) +
        bf2f(w0.y & 0xffff)*bf2f(s0.y & 0xffff) + bf2f(w0.y >> 16)*bf2f(s0.y >> 16) +
        bf2f(w0.z & 0xffff)*bf2f(s0.z & 0xffff) + bf2f(w0.z >> 16)*bf2f(s0.z >> 16) +
        bf2f(w0.w & 0xffff)*bf2f(s0.w & 0xffff) + bf2f(w0.w >> 16)*bf2f(s0.w >> 16) +
        bf2f(w1.x & 0xffff)*bf2f(s1.x & 0xffff) + bf2f(w1.x >> 16)*bf2f(s1.x >> 16) +
        bf2f(w1.y & 0xffff)*bf2f(s1.y & 0xffff) + bf2f(w1.y >> 16)*bf2f(s1.y >> 16) +
        bf2f(w1.z & 0xffff)*bf2f(s1.z & 0xffff) + bf2f(w1.z >> 16)*bf2f(s1.z >> 16) +
        bf2f(w1.w & 0xffff)*bf2f(s1.w & 0xffff) + bf2f(w1.w >> 16)*bf2f(s1.w >> 16);
      d += __shfl_xor(d, 1); d += __shfl_xor(d, 2);
      d += __shfl_xor(d, 4); d += __shfl_xor(d, 8);
      if (l15 == 0) posLt[wid*32 + rl] = d;
    }
    // frag reads: rows p*16+l15, staged by THIS wave (same-wave LDS ordering)
    #pragma unroll
    for (int kf = 0; kf < 8; ++kf){
      const int slot = wid*16 + l15;
      a[p][kf] = *(const bf16x8*)(Ast + slot*512 + ((kf*64 + l4*16) ^ ((l15 & 7) << 4)));
    }
  }

  // row labels nibble-packed: ri = rf*4+e -> wave-local row rf*16 + l4*4 + e
  unsigned Lpack = 0;
  #pragma unroll
  for (int rf = 0; rf < 2; ++rf)
    #pragma unroll
    for (int e = 0; e < 4; ++e)
      Lpack |= ((unsigned)posLb[wid*32 + rf*16 + l4*4 + e]) << ((rf*4 + e)*4);

  float sumT[8], sumO[8];
  #pragma unroll
  for (int i = 0; i < 8; ++i){ sumT[i] = 0.f; sumO[i] = 0.f; }

  __syncthreads();   // A frags read everywhere; Bsh free for B chunks

  stageB(spnP, Ast,         0, tid);   // chunk 0 -> Bsh[0]
  stageB(spnP, Ast + 32768, 1, tid);   // chunk 1 -> Bsh[1]  (depth-2 pipeline)

  const int nChunks = M >> 6;          // 16
  for (int c = 0; c < nChunks; ++c){
    const unsigned cpack = cpLds[c*16 + l15];   // LDS only, no vmcnt interaction
    if (c < nChunks - 1) asm volatile("s_waitcnt vmcnt(4)" ::: "memory");
    else                 asm volatile("s_waitcnt vmcnt(0)" ::: "memory");
    SFENCE(); SBAR(); SFENCE();

    const char* Bp = Ast + (c & 1)*32768;
    #pragma unroll
    for (int cf = 0; cf < 4; ++cf){
      const int colp = cf*16 + l15;
      const int swz  = (l15 & 7) << 4;
      f32x4 acc0 = (f32x4){0.f,0.f,0.f,0.f};
      f32x4 acc1 = (f32x4){0.f,0.f,0.f,0.f};
      #pragma unroll
      for (int kh = 0; kh < 2; ++kh){
        bf16x8 b[4];
        #pragma unroll
        for (int kq = 0; kq < 4; ++kq)
          b[kq] = *(const bf16x8*)(Bp + colp*512 + (((kh*4 + kq)*64 + l4*16) ^ swz));
        #pragma unroll
        for (int kq = 0; kq < 4; ++kq){
          acc0 = __builtin_amdgcn_mfma_f32_16x16x32_bf16(a[0][kh*4+kq], b[kq], acc0, 0, 0, 0);
          acc1 = __builtin_amdgcn_mfma_f32_16x16x32_bf16(a[1][kh*4+kq], b[kq], acc1, 0, 0, 0);
        }
      }
      const unsigned colLab = (cpack >> (cf*4)) & 15u;
      #pragma unroll
      for (int e = 0; e < 4; ++e){
        const float ev0 = __builtin_amdgcn_exp2f(acc0[e]);   // v_exp_f32, no mul
        const float ev1 = __builtin_amdgcn_exp2f(acc1[e]);
        sumT[e]   += ev0;
        sumT[4+e] += ev1;
        sumO[e]   += (((Lpack >> (e*4)) & 15u)       == colLab) ? ev0 : 0.f;
        sumO[4+e] += (((Lpack >> ((4+e)*4)) & 15u)   == colLab) ? ev1 : 0.f;
      }
    }
    SFENCE(); SBAR(); SFENCE();
    if (c + 2 < nChunks) stageB(spnP, (void*)(Ast + (c & 1)*32768), c + 2, tid);
  }

  // reduce over the 16 l15-lanes sharing each row
  #pragma unroll
  for (int i = 0; i < 8; ++i){
    #pragma unroll
    for (int o = 1; o < 16; o <<= 1){
      sumT[i] += __shfl_xor(sumT[i], o);
      sumO[i] += __shfl_xor(sumO[i], o);
    }
  }

  // finish in log2 domain: loss_i = ln2 * (log2(den) - pl2); ln2 folded into k_final
  float part = 0.f;
  #pragma unroll
  for (int rf = 0; rf < 2; ++rf)
    #pragma unroll
    for (int e = 0; e < 4; ++e){
      const float pl  = posLt[wid*32 + rf*16 + l4*4 + e];
      const float ep  = __builtin_amdgcn_exp2f(pl);
      const float den = ep + (sumT[rf*4+e] - sumO[rf*4+e]) + 1e-8f;
      part += __builtin_amdgcn_logf(den) - pl;   // v_log_f32 = log2
    }
  part = (l15 == 0) ? part : 0.f;
  #pragma unroll
  for (int o = 1; o < 64; o <<= 1) part += __shfl_xor(part, o);
  if (lane == 0) atomicAdd(accum, (double)part);
}

__global__ void k_final(const double* __restrict__ accum, float* __restrict__ out, int N){
  // * ln2 (log2->ln) * 0.07 (temperature un-scale) ; LOSS_WEIGHT*TOTAL_WEIGHT
  // note: reference returns loss*0.7*0.1 = loss*0.07; and loss has mean over N.
  out[0] = (float)((*accum / (double)N) * (0.07 * 0.6931471805599453));
}

// ---------------- launch ----------------

extern "C" void kernel_launch(void* const* d_in, const int* in_sizes, int n_in,
                              void* d_out, int out_size, void* d_ws, size_t ws_size,
                              hipStream_t stream){
  const float* sp  = (const float*)d_in[0];
  const float* rp  = (const float*)d_in[1];
  const int*   idx = (const int*)d_in[2];
  const int*   lab = (const int*)d_in[3];
  const int M = in_sizes[0] / DIM;     // 1024
  const int N = in_sizes[2];           // 131072

  char* ws = (char*)d_ws;
  size_t off = 0;
  auto alloc = [&](size_t bytes){ void* p = ws + off; off = (off + bytes + 255) & ~(size_t)255; return p; };
  int*      counts  = (int*)     alloc((size_t)M * NCLS * 4);
  int*      spLabel = (int*)     alloc((size_t)M * 4);
  int*      newpos  = (int*)     alloc((size_t)M * 4);
  unsigned* packLab = (unsigned*)alloc((size_t)(M/64) * 16 * 4);
  double*   accum   = (double*)  alloc(16);
  unsigned short* spnO = (unsigned short*)alloc((size_t)M * DIM * 2);
  unsigned short* spnP = (unsigned short*)alloc((size_t)M * DIM * 2);

  k_zero<<<(M*NCLS + 255)/256, 256, 0, stream>>>(counts, packLab, accum, M*NCLS, (M/64)*16);
  k_hist<<<(N + 255)/256, 256, 0, stream>>>(idx, lab, counts, N);
  k_label_perm<<<1, M, 0, stream>>>(counts, spLabel, newpos, packLab);
  k_norm_sp<<<M, 64, 0, stream>>>(sp, newpos, spnO, spnP);
  k_main<<<N/256, 512, 0, stream>>>(rp, idx, spnO, spnP, packLab, spLabel, accum, M);
  k_final<<<1, 1, 0, stream>>>(accum, (float*)d_out, N);
}